// Round 10
// baseline (220.411 us; speedup 1.0000x reference)
//
#include <hip/hip_runtime.h>

#define BB 4
#define H 320
#define W 768
#define P (H*W)           // 245760
#define NPIX (BB*P)       // 983040
#define P4 (P/4)          // 61440
#define NP4 (NPIX/4)      // 245760

#define TX 32
#define TY 8
#define TW (TX+6)  // 38
#define TH (TY+6)  // 14
#define HALO (TW*TH)      // 532
#define NBX (W/TX)        // 24
#define NBY (H/TY)        // 40
#define NBLK (NBX*NBY*BB) // 3840

#define GRID 1280                  // 5 blocks/CU x 256 CUs, exactly co-resident
#define TPB (NBLK/GRID)            // 3 tiles per block

typedef float f4 __attribute__((ext_vector_type(4)));
typedef unsigned long long u64;

__device__ __forceinline__ float bilinear(const float* __restrict__ img, float fx, float fy) {
    float x0 = floorf(fx), y0 = floorf(fy);
    float wx = fx - x0, wy = fy - y0;
    float x0c = fminf(fmaxf(x0,       0.f), (float)(W - 1));
    float x1c = fminf(fmaxf(x0 + 1.f, 0.f), (float)(W - 1));
    float y0c = fminf(fmaxf(y0,       0.f), (float)(H - 1));
    float y1c = fminf(fmaxf(y0 + 1.f, 0.f), (float)(H - 1));
    int x0i = (int)x0c, x1i = (int)x1c, y0i = (int)y0c, y1i = (int)y1c;
    float Ia = img[y0i * W + x0i], Ib = img[y0i * W + x1i];
    float Ic = img[y1i * W + x0i], Id = img[y1i * W + x1i];
    float omx = 1.f - wx, omy = 1.f - wy;
    return Ia * omx * omy + Ib * wx * omy + Ic * omx * wy + Id * wx * wy;
}

// ONE persistent dispatch:
//   phase 1: gray planes -> ws via relaxed agent-scope (sc1) atomic stores
//            (write-through to LLC; no wbl2/inv -- R8/R9-validated discipline)
//   spin barrier on LLC counter (relaxed fetch_add + relaxed polls).
//            Safe because dispatch-start invalidates L2s (same property the
//            2-kernel version relies on) and gf/gl are never cached pre-barrier.
//   phase 2: TPB tiles/block of the R3-proven census loop (6-trans tap: two
//            INDEPENDENT rsq chains per loss schedule better than the 3-trans
//            rewrite -- R9 measured 147 vs 131 busy-cyc/tap).
//   tail:    validated v3 (sc1 partial stores, vmcnt(0), relaxed done counter,
//            last block reduces in the exact old summation order).
__global__ __launch_bounds__(256, 5)
void fused_all(const float* __restrict__ former, const float* __restrict__ latter,
               const float* __restrict__ flow1, const float* __restrict__ flow2,
               const float* __restrict__ fw_mask, const float* __restrict__ bw_mask,
               float* __restrict__ gf, float* __restrict__ gl,
               float* __restrict__ partials, unsigned* __restrict__ bar,
               unsigned* __restrict__ done, float* __restrict__ out) {
    __shared__ f4 sT[HALO];
    __shared__ float red[8];
    __shared__ unsigned sLast;
    const int tid = threadIdx.x;
    const int wave = tid >> 6, lane = tid & 63;

    // ---------------- phase 1: gray ----------------
    {
        int idx = blockIdx.x * 256 + tid;   // GRID*256 = 327680 >= NP4: single pass
        if (idx < NP4) {
            int b = idx / P4;
            int r4 = idx - b * P4;
            const float* fb = former + (size_t)b * 3 * P;
            const float* lb = latter + (size_t)b * 3 * P;
            const f4 fr = *((const f4*)fb + r4);
            const f4 fg = *((const f4*)(fb + P) + r4);
            const f4 fbl = *((const f4*)(fb + 2 * P) + r4);
            const f4 lr = *((const f4*)lb + r4);
            const f4 lg = *((const f4*)(lb + P) + r4);
            const f4 lbl = *((const f4*)(lb + 2 * P) + r4);
            union { f4 v; u64 u[2]; } cg, cl;
#pragma unroll
            for (int k = 0; k < 4; ++k) {
                cg.v[k] = (0.299f * fr[k] + 0.587f * fg[k] + 0.114f * fbl[k]) * 255.f;
                cl.v[k] = (0.299f * lr[k] + 0.587f * lg[k] + 0.114f * lbl[k]) * 255.f;
            }
            u64* pg = (u64*)((f4*)gf + (size_t)b * P4 + r4);
            u64* pl = (u64*)((f4*)gl + (size_t)b * P4 + r4);
            __hip_atomic_store(pg,     cg.u[0], __ATOMIC_RELAXED, __HIP_MEMORY_SCOPE_AGENT);
            __hip_atomic_store(pg + 1, cg.u[1], __ATOMIC_RELAXED, __HIP_MEMORY_SCOPE_AGENT);
            __hip_atomic_store(pl,     cl.u[0], __ATOMIC_RELAXED, __HIP_MEMORY_SCOPE_AGENT);
            __hip_atomic_store(pl + 1, cl.u[1], __ATOMIC_RELAXED, __HIP_MEMORY_SCOPE_AGENT);
        }
    }
    // every wave drains its own stores to LLC before this block signals arrival
    asm volatile("s_waitcnt vmcnt(0)" ::: "memory");
    __syncthreads();
    if (tid == 0) {
        __hip_atomic_fetch_add(bar, 1u, __ATOMIC_RELAXED, __HIP_MEMORY_SCOPE_AGENT);
        while (__hip_atomic_load(bar, __ATOMIC_RELAXED, __HIP_MEMORY_SCOPE_AGENT) < GRID)
            __builtin_amdgcn_s_sleep(16);
    }
    __syncthreads();

    // ---------------- phase 2: census tiles ----------------
    for (int t = 0; t < TPB; ++t) {
        const int tile = blockIdx.x * TPB + t;     // == old blk index
        const int bx = tile % NBX;
        const int rem = tile / NBX;
        const int by = rem % NBY;
        const int b = rem / NBY;
        const int tx0 = bx * TX, ty0 = by * TY;

        const float* pGF = gf + (size_t)b * P;
        const float* pGL = gl + (size_t)b * P;
        const float* pU1 = flow1 + (size_t)b * 2 * P;
        const float* pU2 = flow2 + (size_t)b * 2 * P;

        for (int i = tid; i < HALO; i += 256) {
            int ly = i / TW, lx = i - ly * TW;
            int gx = min(max(tx0 - 3 + lx, 0), W - 1);
            int gy = min(max(ty0 - 3 + ly, 0), H - 1);
            int o = gy * W + gx;
            float A = pGF[o];
            float C = pGL[o];
            float u1 = pU1[o], v1 = pU1[P + o];
            float u2 = pU2[o], v2 = pU2[P + o];
            float Bv = bilinear(pGL, (float)gx + u1, (float)gy + v1);
            float D  = bilinear(pGF, (float)gx + u2, (float)gy + v2);
            sT[i] = (f4){A, Bv, C, D};
        }
        __syncthreads();

        const int lx = tid & 31, ly = tid >> 5;
        const int x = tx0 + lx, y = ty0 + ly;
        float sum1 = 0.f, sum2 = 0.f;

        if (x >= 3 && x < W - 3 && y >= 3 && y < H - 3) {
            const float m1 = fw_mask[(size_t)b * P + y * W + x];
            const float m2 = bw_mask[(size_t)b * P + y * W + x];
            const int c = (ly + 3) * TW + (lx + 3);
            const f4 cv = sT[c];
            const float c1 = cv.x, c2 = cv.y, c3 = cv.z, c4 = cv.w;
            float acc1a = 0.f, acc1b = 0.f, acc2a = 0.f, acc2b = 0.f;
#pragma unroll
            for (int dy = 0; dy < 7; ++dy) {
                const int ro = (ly + dy) * TW + lx;
#pragma unroll
                for (int dx = 0; dx < 7; ++dx) {
                    if (dy == 3 && dx == 3) continue;   // center tap == 0 exactly
                    const f4 n = sT[ro + dx];           // one ds_read_b128
                    {   // loss 1: two independent rsq chains (R3-proven)
                        const float a  = n.x - c1;
                        const float bb = n.y - c2;
                        const float t1 = a  * __builtin_amdgcn_rsqf(fmaf(a,  a,  0.81f));
                        const float t2 = bb * __builtin_amdgcn_rsqf(fmaf(bb, bb, 0.81f));
                        float d = t1 - t2; d *= d;
                        const float r = __builtin_amdgcn_rcpf(d + 0.1f);
                        if (dx & 1) acc1a = fmaf(d, r, acc1a);
                        else        acc1b = fmaf(d, r, acc1b);
                    }
                    {   // loss 2
                        const float a  = n.z - c3;
                        const float bb = n.w - c4;
                        const float t1 = a  * __builtin_amdgcn_rsqf(fmaf(a,  a,  0.81f));
                        const float t2 = bb * __builtin_amdgcn_rsqf(fmaf(bb, bb, 0.81f));
                        float d = t1 - t2; d *= d;
                        const float r = __builtin_amdgcn_rcpf(d + 0.1f);
                        if (dx & 1) acc2a = fmaf(d, r, acc2a);
                        else        acc2b = fmaf(d, r, acc2b);
                    }
                }
            }
            const float dist1 = acc1a + acc1b;
            const float dist2 = acc2a + acc2b;
            sum1 = exp2f(0.45f * log2f(fmaf(dist1, dist1, 1e-6f))) * m1;
            sum2 = exp2f(0.45f * log2f(fmaf(dist2, dist2, 1e-6f))) * m2;
        }

#pragma unroll
        for (int off = 32; off; off >>= 1) {
            sum1 += __shfl_down(sum1, off, 64);
            sum2 += __shfl_down(sum2, off, 64);
        }
        if (lane == 0) { red[wave] = sum1; red[4 + wave] = sum2; }
        __syncthreads();
        if (tid == 0) {
            // partials -> LLC via relaxed agent-scope atomic stores (no fences)
            __hip_atomic_store(&partials[2 * tile],     red[0] + red[1] + red[2] + red[3],
                               __ATOMIC_RELAXED, __HIP_MEMORY_SCOPE_AGENT);
            __hip_atomic_store(&partials[2 * tile + 1], red[4] + red[5] + red[6] + red[7],
                               __ATOMIC_RELAXED, __HIP_MEMORY_SCOPE_AGENT);
        }
        __syncthreads();   // protect sT/red before next tile
    }

    // ---------------- tail: last block reduces ----------------
    if (tid == 0) {
        asm volatile("s_waitcnt vmcnt(0)" ::: "memory");   // partials at LLC
        unsigned prev = __hip_atomic_fetch_add(done, 1u, __ATOMIC_RELAXED,
                                               __HIP_MEMORY_SCOPE_AGENT);
        sLast = (prev == GRID - 1) ? 1u : 0u;
    }
    __syncthreads();
    if (sLast) {
        float s1 = 0.f, s2 = 0.f;
        for (int i = tid; i < NBLK; i += 256) {
            s1 += __hip_atomic_load(&partials[2 * i],     __ATOMIC_RELAXED, __HIP_MEMORY_SCOPE_AGENT);
            s2 += __hip_atomic_load(&partials[2 * i + 1], __ATOMIC_RELAXED, __HIP_MEMORY_SCOPE_AGENT);
        }
#pragma unroll
        for (int off = 32; off; off >>= 1) {
            s1 += __shfl_down(s1, off, 64);
            s2 += __shfl_down(s2, off, 64);
        }
        __shared__ float red2[8];
        if (lane == 0) { red2[wave] = s1; red2[4 + wave] = s2; }
        __syncthreads();
        if (tid == 0) {
            out[0] = (red2[0] + red2[1] + red2[2] + red2[3]) * (1.0f / NPIX);
            out[1] = (red2[4] + red2[5] + red2[6] + red2[7]) * (1.0f / NPIX);
        }
    }
}

extern "C" void kernel_launch(void* const* d_in, const int* in_sizes, int n_in,
                              void* d_out, int out_size, void* d_ws, size_t ws_size,
                              hipStream_t stream) {
    (void)in_sizes; (void)n_in; (void)out_size; (void)ws_size;
    const float* former  = (const float*)d_in[0];
    const float* latter  = (const float*)d_in[1];
    const float* flow1   = (const float*)d_in[2];
    const float* flow2   = (const float*)d_in[3];
    const float* fw_mask = (const float*)d_in[4];
    const float* bw_mask = (const float*)d_in[5];
    float* out = (float*)d_out;
    float* ws  = (float*)d_ws;
    // layout: partials[2*NBLK] | bar,done (2 uints) | pad | gf[NPIX] | gl[NPIX]
    float* partials   = ws;
    unsigned* bar     = (unsigned*)(ws + 2 * NBLK);      // idx 7680
    unsigned* done    = bar + 1;                         // idx 7681
    float* gf         = ws + 2 * NBLK + 4;               // idx 7684 (16B aligned)
    float* gl         = gf + NPIX;

    hipMemsetAsync(bar, 0, 2 * sizeof(unsigned), stream);
    void* args_unused = nullptr; (void)args_unused;
    fused_all<<<GRID, 256, 0, stream>>>(former, latter, flow1, flow2,
                                        fw_mask, bw_mask, gf, gl,
                                        partials, bar, done, out);
}

// Round 11
// 145.561 us; speedup vs baseline: 1.5142x; 1.5142x over previous
//
#include <hip/hip_runtime.h>

#define BB 4
#define H 320
#define W 768
#define P (H*W)           // 245760
#define NPIX (BB*P)       // 983040
#define P4 (P/4)          // 61440
#define NP4 (NPIX/4)      // 245760

#define TX 32
#define TY 8
#define TW (TX+6)  // 38
#define TH (TY+6)  // 14
#define HALO (TW*TH)      // 532
#define NBX (W/TX)        // 24
#define NBY (H/TY)        // 40
#define NBLK (NBX*NBY*BB) // 3840

typedef float f4 __attribute__((ext_vector_type(4)));

// ---------------- gray kernel (float4-vectorized) ----------------
// Also resets the last-block counter (stream order puts it before fused).
__global__ __launch_bounds__(256)
void gray_kernel(const float* __restrict__ former,
                 const float* __restrict__ latter,
                 float* __restrict__ gf, float* __restrict__ gl,
                 unsigned* __restrict__ counter) {
    int idx = blockIdx.x * blockDim.x + threadIdx.x;
    if (idx == 0) *counter = 0u;
    if (idx >= NP4) return;
    int b = idx / P4;
    int r4 = idx - b * P4;
    const float* fb = former + (size_t)b * 3 * P;
    const float* lb = latter + (size_t)b * 3 * P;
    const f4 fr = *((const f4*)fb + r4);
    const f4 fg = *((const f4*)(fb + P) + r4);
    const f4 fbl = *((const f4*)(fb + 2 * P) + r4);
    const f4 lr = *((const f4*)lb + r4);
    const f4 lg = *((const f4*)(lb + P) + r4);
    const f4 lbl = *((const f4*)(lb + 2 * P) + r4);
    f4 go, lo;
#pragma unroll
    for (int k = 0; k < 4; ++k) {
        go[k] = (0.299f * fr[k] + 0.587f * fg[k] + 0.114f * fbl[k]) * 255.f;
        lo[k] = (0.299f * lr[k] + 0.587f * lg[k] + 0.114f * lbl[k]) * 255.f;
    }
    *((f4*)gf + (size_t)b * P4 + r4) = go;
    *((f4*)gl + (size_t)b * P4 + r4) = lo;
}

__device__ __forceinline__ float bilinear(const float* __restrict__ img, float fx, float fy) {
    float x0 = floorf(fx), y0 = floorf(fy);
    float wx = fx - x0, wy = fy - y0;
    float x0c = fminf(fmaxf(x0,       0.f), (float)(W - 1));
    float x1c = fminf(fmaxf(x0 + 1.f, 0.f), (float)(W - 1));
    float y0c = fminf(fmaxf(y0,       0.f), (float)(H - 1));
    float y1c = fminf(fmaxf(y0 + 1.f, 0.f), (float)(H - 1));
    int x0i = (int)x0c, x1i = (int)x1c, y0i = (int)y0c, y1i = (int)y1c;
    float Ia = img[y0i * W + x0i], Ib = img[y0i * W + x1i];
    float Ic = img[y1i * W + x0i], Id = img[y1i * W + x1i];
    float omx = 1.f - wx, omy = 1.f - wy;
    return Ia * omx * omy + Ib * wx * omy + Ic * omx * wy + Id * wx * wy;
}

// ---------------- fused warp + census + distance + charbonnier + reduce ------
// Structure ledger (what is settled):
//   - 2 dispatches is the floor: single-dispatch needs cross-XCD gray handoff,
//     and all three mechanisms tried (fence storm R4/R6, release wbl2 R7,
//     sc1 write-through R10) cost more than the ~40us dispatch saving.
//   - Tail v3 (validated R8/R9): relaxed sc1 partial stores + s_waitcnt
//     vmcnt(0) + relaxed counter; last block reduces. No wbl2/inv.
//   - (256,5): 44-48 VGPR, zero spill (R8 showed (256,8) spills 187 MB).
// Tap: R3's independent-rsq chains (R9 proved rsq-product chaining costs
// ~16cyc/tap) + ONE shared rcp across the two losses (validated R4/R9):
//   g1 = d1*e2*rcp(e1*e2), g2 = d2*e1*rcp(e1*e2)   -> 5 trans/tap, was 6.
__global__ __launch_bounds__(256, 5)
void fused_kernel(const float* __restrict__ gf, const float* __restrict__ gl,
                  const float* __restrict__ flow1, const float* __restrict__ flow2,
                  const float* __restrict__ fw_mask, const float* __restrict__ bw_mask,
                  float* __restrict__ partials, unsigned* __restrict__ counter,
                  float* __restrict__ out) {
    __shared__ f4 sT[HALO];
    const int b   = blockIdx.z;
    const int tx0 = blockIdx.x * TX;
    const int ty0 = blockIdx.y * TY;
    const int tid = threadIdx.x;

    const float* pGF = gf + (size_t)b * P;
    const float* pGL = gl + (size_t)b * P;
    const float* pU1 = flow1 + (size_t)b * 2 * P;
    const float* pU2 = flow2 + (size_t)b * 2 * P;

    for (int i = tid; i < HALO; i += 256) {
        int ly = i / TW, lx = i - ly * TW;
        int gx = min(max(tx0 - 3 + lx, 0), W - 1);
        int gy = min(max(ty0 - 3 + ly, 0), H - 1);
        int o = gy * W + gx;
        float A = pGF[o];
        float C = pGL[o];
        float u1 = pU1[o], v1 = pU1[P + o];
        float u2 = pU2[o], v2 = pU2[P + o];
        float Bv = bilinear(pGL, (float)gx + u1, (float)gy + v1);
        float D  = bilinear(pGF, (float)gx + u2, (float)gy + v2);
        sT[i] = (f4){A, Bv, C, D};
    }
    __syncthreads();

    const int lx = tid & 31, ly = tid >> 5;
    const int x = tx0 + lx, y = ty0 + ly;
    float sum1 = 0.f, sum2 = 0.f;

    if (x >= 3 && x < W - 3 && y >= 3 && y < H - 3) {
        const float m1 = fw_mask[(size_t)b * P + y * W + x];
        const float m2 = bw_mask[(size_t)b * P + y * W + x];
        const int c = (ly + 3) * TW + (lx + 3);
        const f4 cv = sT[c];
        const float c1 = cv.x, c2 = cv.y, c3 = cv.z, c4 = cv.w;
        float acc1a = 0.f, acc1b = 0.f, acc2a = 0.f, acc2b = 0.f;
#pragma unroll
        for (int dy = 0; dy < 7; ++dy) {
            const int ro = (ly + dy) * TW + lx;
#pragma unroll
            for (int dx = 0; dx < 7; ++dx) {
                if (dy == 3 && dx == 3) continue;    // center tap == 0 exactly
                const f4 n = sT[ro + dx];            // one ds_read_b128
                // loss 1: two INDEPENDENT rsq chains (R3-proven scheduling)
                const float a1 = n.x - c1, b1 = n.y - c2;
                const float t11 = a1 * __builtin_amdgcn_rsqf(fmaf(a1, a1, 0.81f));
                const float t12 = b1 * __builtin_amdgcn_rsqf(fmaf(b1, b1, 0.81f));
                float d1 = t11 - t12; d1 *= d1;
                // loss 2
                const float a2 = n.z - c3, b2 = n.w - c4;
                const float t21 = a2 * __builtin_amdgcn_rsqf(fmaf(a2, a2, 0.81f));
                const float t22 = b2 * __builtin_amdgcn_rsqf(fmaf(b2, b2, 0.81f));
                float d2 = t21 - t22; d2 *= d2;
                // ONE rcp shared across the two losses (validated R4/R9)
                const float e1 = d1 + 0.1f, e2 = d2 + 0.1f;
                const float ir = __builtin_amdgcn_rcpf(e1 * e2);
                const float g1 = (d1 * e2) * ir;
                const float g2 = (d2 * e1) * ir;
                if (dx & 1) { acc1a += g1; acc2a += g2; }
                else        { acc1b += g1; acc2b += g2; }
            }
        }
        const float dist1 = acc1a + acc1b;
        const float dist2 = acc2a + acc2b;
        sum1 = exp2f(0.45f * log2f(fmaf(dist1, dist1, 1e-6f))) * m1;
        sum2 = exp2f(0.45f * log2f(fmaf(dist2, dist2, 1e-6f))) * m2;
    }

#pragma unroll
    for (int off = 32; off; off >>= 1) {
        sum1 += __shfl_down(sum1, off, 64);
        sum2 += __shfl_down(sum2, off, 64);
    }
    __shared__ float red[8];
    const int wave = tid >> 6, lane = tid & 63;
    if (lane == 0) { red[wave] = sum1; red[4 + wave] = sum2; }
    __syncthreads();

    __shared__ unsigned sLast;
    if (tid == 0) {
        const int blk = (blockIdx.z * NBY + blockIdx.y) * NBX + blockIdx.x;
        // partials -> LLC via relaxed agent-scope atomic stores (no fences)
        __hip_atomic_store(&partials[2 * blk],     red[0] + red[1] + red[2] + red[3],
                           __ATOMIC_RELAXED, __HIP_MEMORY_SCOPE_AGENT);
        __hip_atomic_store(&partials[2 * blk + 1], red[4] + red[5] + red[6] + red[7],
                           __ATOMIC_RELAXED, __HIP_MEMORY_SCOPE_AGENT);
        // HW ordering: stores acked at LLC before the counter bump issues.
        asm volatile("s_waitcnt vmcnt(0)" ::: "memory");
        unsigned prev = __hip_atomic_fetch_add(counter, 1u, __ATOMIC_RELAXED,
                                               __HIP_MEMORY_SCOPE_AGENT);
        sLast = (prev == NBLK - 1) ? 1u : 0u;
    }
    __syncthreads();
    if (sLast) {
        float s1 = 0.f, s2 = 0.f;
        for (int i = tid; i < NBLK; i += 256) {
            s1 += __hip_atomic_load(&partials[2 * i],     __ATOMIC_RELAXED, __HIP_MEMORY_SCOPE_AGENT);
            s2 += __hip_atomic_load(&partials[2 * i + 1], __ATOMIC_RELAXED, __HIP_MEMORY_SCOPE_AGENT);
        }
#pragma unroll
        for (int off = 32; off; off >>= 1) {
            s1 += __shfl_down(s1, off, 64);
            s2 += __shfl_down(s2, off, 64);
        }
        __shared__ float red2[8];
        if (lane == 0) { red2[wave] = s1; red2[4 + wave] = s2; }
        __syncthreads();
        if (tid == 0) {
            out[0] = (red2[0] + red2[1] + red2[2] + red2[3]) * (1.0f / NPIX);
            out[1] = (red2[4] + red2[5] + red2[6] + red2[7]) * (1.0f / NPIX);
        }
    }
}

extern "C" void kernel_launch(void* const* d_in, const int* in_sizes, int n_in,
                              void* d_out, int out_size, void* d_ws, size_t ws_size,
                              hipStream_t stream) {
    (void)in_sizes; (void)n_in; (void)out_size; (void)ws_size;
    const float* former  = (const float*)d_in[0];
    const float* latter  = (const float*)d_in[1];
    const float* flow1   = (const float*)d_in[2];
    const float* flow2   = (const float*)d_in[3];
    const float* fw_mask = (const float*)d_in[4];
    const float* bw_mask = (const float*)d_in[5];
    float* out = (float*)d_out;
    float* ws  = (float*)d_ws;
    float* gf       = ws;                         // NPIX floats
    float* gl       = ws + NPIX;                  // NPIX floats
    float* partials = ws + 2 * (size_t)NPIX;      // 2*NBLK floats
    unsigned* counter = (unsigned*)(ws + 2 * (size_t)NPIX + 2 * NBLK);

    gray_kernel<<<(NP4 + 255) / 256, 256, 0, stream>>>(former, latter, gf, gl, counter);
    fused_kernel<<<dim3(NBX, NBY, BB), 256, 0, stream>>>(gf, gl, flow1, flow2,
                                                         fw_mask, bw_mask,
                                                         partials, counter, out);
}